// Round 2
// baseline (241.811 us; speedup 1.0000x reference)
//
#include <hip/hip_runtime.h>
#include <hip/hip_bf16.h>
#include <cstdint>

typedef __attribute__((ext_vector_type(8))) short bf16x8;
typedef __attribute__((ext_vector_type(4))) float f32x4;
typedef __attribute__((ext_vector_type(4))) unsigned int u32x4;
typedef __attribute__((ext_vector_type(8))) unsigned short u16x8;

#define DEV static __device__ __forceinline__

DEV unsigned short f2b(float x) {
    __hip_bfloat16 b = __float2bfloat16(x);
    return __builtin_bit_cast(unsigned short, b);
}
DEV float b2f(unsigned short u) {
    __hip_bfloat16 b = __builtin_bit_cast(__hip_bfloat16, u);
    return __bfloat162float(b);
}

// ---------------------------------------------------------------------------
// prep: fold BN into weights, transpose to [N][K]; q-scale folded into q cols
// ---------------------------------------------------------------------------
__global__ void prep_w_qkv(const float* __restrict__ w, const float* __restrict__ g,
                           const float* __restrict__ be, const float* __restrict__ mu,
                           const float* __restrict__ va, unsigned short* __restrict__ wT,
                           float* __restrict__ t1)
{
    int gid = blockIdx.x * 256 + threadIdx.x;   // 384*1024 threads
    int c = gid & 1023, k = gid >> 10;
    float s = g[c] * rsqrtf(va[c] + 1e-5f);
    float qs = ((c & 127) < 32) ? 0.17677669529663687f : 1.0f; // fold SCALE into q
    float val = w[(size_t)k * 1024 + c] * s * qs;
    wT[(size_t)c * 384 + k] = f2b(val);
    if (k == 0) t1[c] = (be[c] - mu[c] * s) * qs;
}

// proj weights: hi/lo split, augmented K' = [hi | lo | hi] (pairs with O = [hi|hi|lo])
__global__ void prep_w_proj(const float* __restrict__ w, const float* __restrict__ g,
                            const float* __restrict__ be, const float* __restrict__ mu,
                            const float* __restrict__ va, unsigned short* __restrict__ wT,
                            float* __restrict__ t2)
{
    int gid = blockIdx.x * 256 + threadIdx.x;   // 512*384 threads
    int c = gid % 384, k = gid / 384;
    float s = g[c] * rsqrtf(va[c] + 1e-5f);
    float val = w[(size_t)k * 384 + c] * s;
    unsigned short hi = f2b(val);
    unsigned short lo = f2b(val - b2f(hi));
    size_t base = (size_t)c * 1536;
    wT[base + k]        = hi;
    wT[base + 512 + k]  = lo;
    wT[base + 1024 + k] = hi;
    if (k == 0) t2[c] = be[c] - mu[c] * s;
}

// ---------------------------------------------------------------------------
// GEMM: C[M,N] = A[M,K] * Bt[N,K]^T (+tvec[col]).  2-barrier loop, reg staging.
// AF32=1: A is fp32, converted to bf16 during LDS commit (fuses prep_x).
// EPI=0: scatter to q/k/v bf16.  EPI=1: fp32 out (proj).
// ---------------------------------------------------------------------------
template<int BM, int BN, int EPI, int AF32>
__launch_bounds__(256, 2)
__global__ void gemm_bt(const void* __restrict__ Av,
                        const unsigned short* __restrict__ Bt,
                        int Kdim,
                        const float* __restrict__ tvec,
                        unsigned short* __restrict__ outq,
                        unsigned short* __restrict__ outk,
                        unsigned short* __restrict__ outv,
                        float* __restrict__ outf)
{
    constexpr int BK = 64;
    constexpr int WM = BM / 2, WN = BN / 2;
    constexpr int MI = WM / 16, NI = WN / 16;
    constexpr int RA = BM * BK / 2048;   // 8-elem chunks per thread for A tile
    constexpr int RB = BN * BK / 2048;

    const unsigned short* Ab = (const unsigned short*)Av;
    const float* Af = (const float*)Av;

    __shared__ __align__(16) unsigned short As[BM * BK];
    __shared__ __align__(16) unsigned short Bs[BN * BK];

    const int tid = threadIdx.x;
    const int lane = tid & 63, w = tid >> 6;
    const int l15 = lane & 15, lg = lane >> 4;
    const int wr = w >> 1, wc = w & 1;
    const int m0 = blockIdx.x * BM;
    const int n0 = blockIdx.y * BN;

    f32x4 acc[MI][NI];
    #pragma unroll
    for (int i = 0; i < MI; ++i)
        #pragma unroll
        for (int j = 0; j < NI; ++j) acc[i][j] = (f32x4){0.f, 0.f, 0.f, 0.f};

    u32x4 ra[AF32 ? 1 : RA], rb[RB];
    f32x4 raf[AF32 ? RA : 1][2];
    const int nk = Kdim / BK;

    auto load_tiles = [&](int k0) {
        #pragma unroll
        for (int i = 0; i < RA; ++i) {
            int off = (i * 256 + tid) * 8;
            int row = off >> 6, col = off & 63;
            if constexpr (AF32) {
                const float* ap = Af + (size_t)(m0 + row) * Kdim + k0 + col;
                raf[i][0] = *(const f32x4*)(ap);
                raf[i][1] = *(const f32x4*)(ap + 4);
            } else {
                ra[i] = *(const u32x4*)(Ab + (size_t)(m0 + row) * Kdim + k0 + col);
            }
        }
        #pragma unroll
        for (int i = 0; i < RB; ++i) {
            int off = (i * 256 + tid) * 8;
            int row = off >> 6, col = off & 63;
            rb[i] = *(const u32x4*)(Bt + (size_t)(n0 + row) * Kdim + k0 + col);
        }
    };

    load_tiles(0);
    for (int kb = 0; kb < nk; ++kb) {
        __syncthreads();
        #pragma unroll
        for (int i = 0; i < RA; ++i) {
            if constexpr (AF32) {
                u16x8 o;
                const float* f = (const float*)&raf[i][0];
                #pragma unroll
                for (int t = 0; t < 8; ++t) o[t] = f2b(f[t]);
                *(u16x8*)(&As[(i * 256 + tid) * 8]) = o;
            } else {
                *(u32x4*)(&As[(i * 256 + tid) * 8]) = ra[i];
            }
        }
        #pragma unroll
        for (int i = 0; i < RB; ++i) *(u32x4*)(&Bs[(i * 256 + tid) * 8]) = rb[i];
        __syncthreads();
        if (kb + 1 < nk) load_tiles((kb + 1) * BK);   // prefetch next tile
        #pragma unroll
        for (int ks = 0; ks < 2; ++ks) {
            bf16x8 af[MI], bfr[NI];
            #pragma unroll
            for (int mi = 0; mi < MI; ++mi)
                af[mi] = *(const bf16x8*)(&As[(wr * WM + mi * 16 + l15) * 64 + ks * 32 + lg * 8]);
            #pragma unroll
            for (int ni = 0; ni < NI; ++ni)
                bfr[ni] = *(const bf16x8*)(&Bs[(wc * WN + ni * 16 + l15) * 64 + ks * 32 + lg * 8]);
            #pragma unroll
            for (int mi = 0; mi < MI; ++mi)
                #pragma unroll
                for (int ni = 0; ni < NI; ++ni)
                    acc[mi][ni] = __builtin_amdgcn_mfma_f32_16x16x32_bf16(
                        af[mi], bfr[ni], acc[mi][ni], 0, 0, 0);
        }
    }

    #pragma unroll
    for (int mi = 0; mi < MI; ++mi)
    #pragma unroll
    for (int ni = 0; ni < NI; ++ni)
    #pragma unroll
    for (int j = 0; j < 4; ++j) {
        int row = m0 + wr * WM + mi * 16 + lg * 4 + j;   // C/D: row=(lane>>4)*4+reg
        int col = n0 + wc * WN + ni * 16 + l15;          //      col=lane&15
        float val = acc[mi][ni][j] + tvec[col];
        if constexpr (EPI == 0) {
            int bb = row >> 10, n = row & 1023;
            int hh = col >> 7, t = col & 127;
            size_t base = (size_t)(bb * 8 + hh) * 1024 + n;
            unsigned short bv = f2b(val);
            if (t < 32)       outq[base * 32 + t] = bv;
            else if (t < 64)  outk[base * 32 + (t - 32)] = bv;
            else              outv[base * 64 + (t - 64)] = bv;
        } else {
            outf[(size_t)row * 384 + col] = val;
        }
    }
}

// ---------------------------------------------------------------------------
// v[bh][n][64] -> vt[bh][64][n]  (LDS tile transpose, coalesced both sides)
// ---------------------------------------------------------------------------
__global__ void vtrans_kernel(const unsigned short* __restrict__ v,
                              unsigned short* __restrict__ vt)
{
    __shared__ __align__(16) unsigned short tile[64][80];
    int bh = blockIdx.x, nb = blockIdx.y, t = threadIdx.x;
    #pragma unroll
    for (int rep = 0; rep < 2; ++rep) {
        int nl = (t >> 3) + rep * 32;
        int c0 = (t & 7) * 8;
        *(u32x4*)(&tile[nl][c0]) =
            *(const u32x4*)(v + ((size_t)bh * 1024 + nb * 64 + nl) * 64 + c0);
    }
    __syncthreads();
    #pragma unroll
    for (int rep = 0; rep < 2; ++rep) {
        int vd = (t >> 3) + rep * 32;
        int n0 = (t & 7) * 8;
        u16x8 o;
        #pragma unroll
        for (int i = 0; i < 8; ++i) o[i] = tile[n0 + i][vd];
        *(u16x8*)(vt + ((size_t)bh * 64 + vd) * 1024 + nb * 64 + n0) = o;
    }
}

// ---------------------------------------------------------------------------
// fused flash attention, barrier-free: wg = (qblk64, h, b), 4 waves x 16 rows.
// K and V^T B-frags straight from global (L1/L2-resident per bh).
// bias folded in as MFMA C-in; row-sum via ones-column MFMA; defer-max (THR=8).
// epilogue: /lsum, hardswish, hi/lo split -> Oaug[tok][1536]
// ---------------------------------------------------------------------------
__launch_bounds__(256, 4)
__global__ void attn_kernel(const unsigned short* __restrict__ q,
                            const unsigned short* __restrict__ kmat,
                            const unsigned short* __restrict__ vt,
                            const float* __restrict__ ab,
                            unsigned short* __restrict__ Oaug)
{
    __shared__ __align__(16) unsigned short Pls[4 * 16 * 64]; // per-wave P
    __shared__ float biasrow[1024];

    const int tid = threadIdx.x;
    const int lane = tid & 63, w = tid >> 6;
    const int l15 = lane & 15, lg = lane >> 4;
    const int qb = blockIdx.x, h = blockIdx.y, b = blockIdx.z;
    const int bh = b * 8 + h;

    for (int i = tid; i < 1024; i += 256) biasrow[i] = ab[h * 1024 + i];
    __syncthreads();   // the only barrier: biasrow visibility

    // Q A-frag (A: row=lane&15, k=(lane>>4)*8+i) — resident whole kernel
    const int qrowA = qb * 64 + w * 16 + l15;
    const bf16x8 aq = *(const bf16x8*)(q + ((size_t)bh * 1024 + qrowA) * 32 + lg * 8);

    // D-layout q-rows for this lane: qi = qb*64 + w*16 + lg*4 + j
    int xi[4], dy2[2][4];
    #pragma unroll
    for (int j = 0; j < 4; ++j) {
        int qi = qb * 64 + w * 16 + lg * 4 + j;
        xi[j] = qi >> 5;
        int yi = qi & 31;
        #pragma unroll
        for (int p = 0; p < 2; ++p) {
            int d = yi - (p * 16 + l15);
            dy2[p][j] = d < 0 ? -d : d;
        }
    }

    float m[4];
    f32x4 acc[4], accS;
    #pragma unroll
    for (int j = 0; j < 4; ++j) m[j] = -1e30f;
    #pragma unroll
    for (int cf = 0; cf < 4; ++cf) acc[cf] = (f32x4){0.f, 0.f, 0.f, 0.f};
    accS = (f32x4){0.f, 0.f, 0.f, 0.f};

    const short oneb = (short)0x3F80;
    const bf16x8 onesb = {oneb, oneb, oneb, oneb, oneb, oneb, oneb, oneb};

    const unsigned short* kbase = kmat + (size_t)bh * 1024 * 32 + lg * 8;
    const unsigned short* vbase = vt + (size_t)bh * 64 * 1024 + lg * 8;

    for (int kb = 0; kb < 16; ++kb) {
        // QK^T with bias as C-in (B-frag from global k, L1-shared across waves)
        f32x4 s[4];
        __builtin_amdgcn_s_setprio(1);
        #pragma unroll
        for (int cf = 0; cf < 4; ++cf) {
            int xj = kb * 2 + (cf >> 1);
            f32x4 c;
            #pragma unroll
            for (int j = 0; j < 4; ++j) {
                int dx = xi[j] - xj; dx = dx < 0 ? -dx : dx;
                c[j] = biasrow[dx * 32 + dy2[cf & 1][j]];
            }
            const bf16x8 bk = *(const bf16x8*)(kbase + (size_t)(kb * 64 + cf * 16 + l15) * 32);
            s[cf] = __builtin_amdgcn_mfma_f32_16x16x32_bf16(aq, bk, c, 0, 0, 0);
        }
        __builtin_amdgcn_s_setprio(0);

        // row max (in-lane over cf, then 4-round shfl over l15)
        float nm[4];
        #pragma unroll
        for (int j = 0; j < 4; ++j) {
            float rm = fmaxf(fmaxf(s[0][j], s[1][j]), fmaxf(s[2][j], s[3][j]));
            rm = fmaxf(rm, __shfl_xor(rm, 1));
            rm = fmaxf(rm, __shfl_xor(rm, 2));
            rm = fmaxf(rm, __shfl_xor(rm, 4));
            rm = fmaxf(rm, __shfl_xor(rm, 8));
            nm[j] = rm;
        }
        // defer-max: only rescale when some row grew past THR=8
        bool grow = (nm[0] > m[0] + 8.f) | (nm[1] > m[1] + 8.f) |
                    (nm[2] > m[2] + 8.f) | (nm[3] > m[3] + 8.f);
        if (__any(grow)) {
            #pragma unroll
            for (int j = 0; j < 4; ++j) {
                float M = fmaxf(m[j], nm[j]);
                float al = __expf(m[j] - M);
                m[j] = M;
                #pragma unroll
                for (int cf = 0; cf < 4; ++cf) acc[cf][j] *= al;
                accS[j] *= al;
            }
        }

        // P = exp(s - m) -> per-wave LDS (bf16, XOR-swizzled rows)
        #pragma unroll
        for (int j = 0; j < 4; ++j) {
            int qrl = lg * 4 + j;
            int rxor = (qrl & 7) << 4;
            #pragma unroll
            for (int cf = 0; cf < 4; ++cf) {
                float pv = __expf(s[cf][j] - m[j]);
                *(unsigned short*)((char*)Pls + w * 2048 + qrl * 128 +
                                   ((cf * 32 + l15 * 2) ^ rxor)) = f2b(pv);
            }
        }
        __asm__ volatile("s_waitcnt lgkmcnt(0)" ::: "memory");

        // PV: A-frag = P rows (LDS), B-frag = V^T rows straight from global;
        // ones-column MFMA accumulates the row sums into accS (rides rescale).
        __builtin_amdgcn_s_setprio(1);
        #pragma unroll
        for (int ks = 0; ks < 2; ++ks) {
            const bf16x8 pa = *(const bf16x8*)((char*)Pls + w * 2048 + l15 * 128 +
                                               ((ks * 64 + lg * 16) ^ ((l15 & 7) << 4)));
            accS = __builtin_amdgcn_mfma_f32_16x16x32_bf16(pa, onesb, accS, 0, 0, 0);
            #pragma unroll
            for (int cf = 0; cf < 4; ++cf) {
                const bf16x8 vb = *(const bf16x8*)(
                    vbase + (size_t)(cf * 16 + l15) * 1024 + kb * 64 + ks * 32);
                acc[cf] = __builtin_amdgcn_mfma_f32_16x16x32_bf16(pa, vb, acc[cf], 0, 0, 0);
            }
        }
        __builtin_amdgcn_s_setprio(0);
    }

    // epilogue: normalize, hardswish, hi/lo split into augmented activations
    float rinv[4];
    #pragma unroll
    for (int j = 0; j < 4; ++j) rinv[j] = 1.f / accS[j];
    #pragma unroll
    for (int cf = 0; cf < 4; ++cf)
    #pragma unroll
    for (int j = 0; j < 4; ++j) {
        float ov = acc[cf][j] * rinv[j];
        float hs = ov * fminf(fmaxf(ov + 3.f, 0.f), 6.f) * (1.f / 6.f);
        unsigned short hi = f2b(hs);
        unsigned short lo = f2b(hs - b2f(hi));
        size_t tok = (size_t)b * 1024 + qb * 64 + w * 16 + lg * 4 + j;
        int c = h * 64 + cf * 16 + l15;
        Oaug[tok * 1536 + c]        = hi;
        Oaug[tok * 1536 + 512 + c]  = hi;
        Oaug[tok * 1536 + 1024 + c] = lo;
    }
}

// ---------------------------------------------------------------------------
extern "C" void kernel_launch(void* const* d_in, const int* in_sizes, int n_in,
                              void* d_out, int out_size, void* d_ws, size_t ws_size,
                              hipStream_t stream)
{
    const float* x   = (const float*)d_in[0];
    const float* qw  = (const float*)d_in[1];
    const float* qg  = (const float*)d_in[2];
    const float* qbe = (const float*)d_in[3];
    const float* qmu = (const float*)d_in[4];
    const float* qva = (const float*)d_in[5];
    const float* pw  = (const float*)d_in[6];
    const float* pg  = (const float*)d_in[7];
    const float* pbe = (const float*)d_in[8];
    const float* pmu = (const float*)d_in[9];
    const float* pva = (const float*)d_in[10];
    const float* ab  = (const float*)d_in[11];
    // d_in[12] (bias_idxs) replicated arithmetically in-kernel

    char* ws = (char*)d_ws;
    size_t off = 0;
    auto alloc = [&](size_t bytes) {
        size_t o = off; off = (off + bytes + 255) & ~(size_t)255; return o;
    };

    size_t o_oaug = alloc((size_t)16384 * 1536 * 2); // Oaug (hi|hi|lo)
    size_t o_wT  = alloc((size_t)1024 * 384 * 2);
    size_t o_pwT = alloc((size_t)384 * 1536 * 2);
    size_t o_t1  = alloc(1024 * 4);
    size_t o_t2  = alloc(384 * 4);
    size_t o_q   = alloc((size_t)16 * 8 * 1024 * 32 * 2);
    size_t o_k   = alloc((size_t)16 * 8 * 1024 * 32 * 2);
    size_t o_v   = alloc((size_t)16 * 8 * 1024 * 64 * 2);
    size_t o_vt  = alloc((size_t)16 * 8 * 1024 * 64 * 2);

    unsigned short* Oaug = (unsigned short*)(ws + o_oaug);
    unsigned short* wT   = (unsigned short*)(ws + o_wT);
    unsigned short* pwT  = (unsigned short*)(ws + o_pwT);
    float* t1 = (float*)(ws + o_t1);
    float* t2 = (float*)(ws + o_t2);
    unsigned short* qb_ = (unsigned short*)(ws + o_q);
    unsigned short* kb_ = (unsigned short*)(ws + o_k);
    unsigned short* vb_ = (unsigned short*)(ws + o_v);
    unsigned short* vtb = (unsigned short*)(ws + o_vt);

    prep_w_qkv<<<1536, 256, 0, stream>>>(qw, qg, qbe, qmu, qva, wT, t1);
    prep_w_proj<<<768, 256, 0, stream>>>(pw, pg, pbe, pmu, pva, pwT, t2);

    // qkv GEMM with fused fp32->bf16 A-staging (prep_x eliminated)
    gemm_bt<128, 128, 0, 1><<<dim3(128, 8), 256, 0, stream>>>(
        x, wT, 384, t1, qb_, kb_, vb_, nullptr);

    vtrans_kernel<<<dim3(128, 16), 256, 0, stream>>>(vb_, vtb);

    attn_kernel<<<dim3(16, 8, 16), 256, 0, stream>>>(qb_, kb_, vtb, ab, Oaug);

    gemm_bt<64, 128, 1, 0><<<dim3(256, 3), 256, 0, stream>>>(
        Oaug, pwT, 1536, t2, nullptr, nullptr, nullptr, (float*)d_out);
}

// Round 3
// 171.039 us; speedup vs baseline: 1.4138x; 1.4138x over previous
//
#include <hip/hip_runtime.h>
#include <hip/hip_bf16.h>
#include <cstdint>

typedef __attribute__((ext_vector_type(8))) short bf16x8;
typedef __attribute__((ext_vector_type(4))) float f32x4;
typedef __attribute__((ext_vector_type(4))) unsigned int u32x4;
typedef __attribute__((ext_vector_type(8))) unsigned short u16x8;

#define DEV static __device__ __forceinline__

DEV unsigned short f2b(float x) {
    __hip_bfloat16 b = __float2bfloat16(x);
    return __builtin_bit_cast(unsigned short, b);
}
DEV float b2f(unsigned short u) {
    __hip_bfloat16 b = __builtin_bit_cast(__hip_bfloat16, u);
    return __bfloat162float(b);
}

// ---------------------------------------------------------------------------
// prep: fold BN into weights, transpose to [N][K]; q-scale folded into q cols
// ---------------------------------------------------------------------------
__global__ void prep_w_qkv(const float* __restrict__ w, const float* __restrict__ g,
                           const float* __restrict__ be, const float* __restrict__ mu,
                           const float* __restrict__ va, unsigned short* __restrict__ wT,
                           float* __restrict__ t1)
{
    int gid = blockIdx.x * 256 + threadIdx.x;   // 384*1024 threads
    int c = gid & 1023, k = gid >> 10;
    float s = g[c] * rsqrtf(va[c] + 1e-5f);
    float qs = ((c & 127) < 32) ? 0.17677669529663687f : 1.0f; // fold SCALE into q
    float val = w[(size_t)k * 1024 + c] * s * qs;
    wT[(size_t)c * 384 + k] = f2b(val);
    if (k == 0) t1[c] = (be[c] - mu[c] * s) * qs;
}

// proj weights: hi/lo split, augmented K' = [hi | lo | hi] (pairs with O = [hi|hi|lo])
__global__ void prep_w_proj(const float* __restrict__ w, const float* __restrict__ g,
                            const float* __restrict__ be, const float* __restrict__ mu,
                            const float* __restrict__ va, unsigned short* __restrict__ wT,
                            float* __restrict__ t2)
{
    int gid = blockIdx.x * 256 + threadIdx.x;   // 512*384 threads
    int c = gid % 384, k = gid / 384;
    float s = g[c] * rsqrtf(va[c] + 1e-5f);
    float val = w[(size_t)k * 384 + c] * s;
    unsigned short hi = f2b(val);
    unsigned short lo = f2b(val - b2f(hi));
    size_t base = (size_t)c * 1536;
    wT[base + k]        = hi;
    wT[base + 512 + k]  = lo;
    wT[base + 1024 + k] = hi;
    if (k == 0) t2[c] = be[c] - mu[c] * s;
}

// ---------------------------------------------------------------------------
// GEMM: C[M,N] = A[M,K] * Bt[N,K]^T (+tvec[col]).  2-barrier loop, reg staging.
// AF32=1: A is fp32, converted to bf16 during LDS commit (fuses prep_x).
// EPI=0: scatter to q/k/v bf16.  EPI=1: fp32 out (proj).
// ---------------------------------------------------------------------------
template<int BM, int BN, int EPI, int AF32>
__launch_bounds__(256, 2)
__global__ void gemm_bt(const void* __restrict__ Av,
                        const unsigned short* __restrict__ Bt,
                        int Kdim,
                        const float* __restrict__ tvec,
                        unsigned short* __restrict__ outq,
                        unsigned short* __restrict__ outk,
                        unsigned short* __restrict__ outv,
                        float* __restrict__ outf)
{
    constexpr int BK = 64;
    constexpr int WM = BM / 2, WN = BN / 2;
    constexpr int MI = WM / 16, NI = WN / 16;
    constexpr int RA = BM * BK / 2048;   // 8-elem chunks per thread for A tile
    constexpr int RB = BN * BK / 2048;

    const unsigned short* Ab = (const unsigned short*)Av;
    const float* Af = (const float*)Av;

    __shared__ __align__(16) unsigned short As[BM * BK];
    __shared__ __align__(16) unsigned short Bs[BN * BK];

    const int tid = threadIdx.x;
    const int lane = tid & 63, w = tid >> 6;
    const int l15 = lane & 15, lg = lane >> 4;
    const int wr = w >> 1, wc = w & 1;
    const int m0 = blockIdx.x * BM;
    const int n0 = blockIdx.y * BN;

    f32x4 acc[MI][NI];
    #pragma unroll
    for (int i = 0; i < MI; ++i)
        #pragma unroll
        for (int j = 0; j < NI; ++j) acc[i][j] = (f32x4){0.f, 0.f, 0.f, 0.f};

    u32x4 ra[AF32 ? 1 : RA], rb[RB];
    f32x4 raf[AF32 ? RA : 1][2];
    const int nk = Kdim / BK;

    auto load_tiles = [&](int k0) {
        #pragma unroll
        for (int i = 0; i < RA; ++i) {
            int off = (i * 256 + tid) * 8;
            int row = off >> 6, col = off & 63;
            if constexpr (AF32) {
                const float* ap = Af + (size_t)(m0 + row) * Kdim + k0 + col;
                raf[i][0] = *(const f32x4*)(ap);
                raf[i][1] = *(const f32x4*)(ap + 4);
            } else {
                ra[i] = *(const u32x4*)(Ab + (size_t)(m0 + row) * Kdim + k0 + col);
            }
        }
        #pragma unroll
        for (int i = 0; i < RB; ++i) {
            int off = (i * 256 + tid) * 8;
            int row = off >> 6, col = off & 63;
            rb[i] = *(const u32x4*)(Bt + (size_t)(n0 + row) * Kdim + k0 + col);
        }
    };

    load_tiles(0);
    for (int kb = 0; kb < nk; ++kb) {
        __syncthreads();
        #pragma unroll
        for (int i = 0; i < RA; ++i) {
            if constexpr (AF32) {
                u16x8 o;
                const float* f = (const float*)&raf[i][0];
                #pragma unroll
                for (int t = 0; t < 8; ++t) o[t] = f2b(f[t]);
                *(u16x8*)(&As[(i * 256 + tid) * 8]) = o;
            } else {
                *(u32x4*)(&As[(i * 256 + tid) * 8]) = ra[i];
            }
        }
        #pragma unroll
        for (int i = 0; i < RB; ++i) *(u32x4*)(&Bs[(i * 256 + tid) * 8]) = rb[i];
        __syncthreads();
        if (kb + 1 < nk) load_tiles((kb + 1) * BK);   // prefetch next tile
        #pragma unroll
        for (int ks = 0; ks < 2; ++ks) {
            bf16x8 af[MI], bfr[NI];
            #pragma unroll
            for (int mi = 0; mi < MI; ++mi)
                af[mi] = *(const bf16x8*)(&As[(wr * WM + mi * 16 + l15) * 64 + ks * 32 + lg * 8]);
            #pragma unroll
            for (int ni = 0; ni < NI; ++ni)
                bfr[ni] = *(const bf16x8*)(&Bs[(wc * WN + ni * 16 + l15) * 64 + ks * 32 + lg * 8]);
            #pragma unroll
            for (int mi = 0; mi < MI; ++mi)
                #pragma unroll
                for (int ni = 0; ni < NI; ++ni)
                    acc[mi][ni] = __builtin_amdgcn_mfma_f32_16x16x32_bf16(
                        af[mi], bfr[ni], acc[mi][ni], 0, 0, 0);
        }
    }

    #pragma unroll
    for (int mi = 0; mi < MI; ++mi)
    #pragma unroll
    for (int ni = 0; ni < NI; ++ni)
    #pragma unroll
    for (int j = 0; j < 4; ++j) {
        int row = m0 + wr * WM + mi * 16 + lg * 4 + j;   // C/D: row=(lane>>4)*4+reg
        int col = n0 + wc * WN + ni * 16 + l15;          //      col=lane&15
        float val = acc[mi][ni][j] + tvec[col];
        if constexpr (EPI == 0) {
            int bb = row >> 10, n = row & 1023;
            int hh = col >> 7, t = col & 127;
            size_t base = (size_t)(bb * 8 + hh) * 1024 + n;
            unsigned short bv = f2b(val);
            if (t < 32)       outq[base * 32 + t] = bv;
            else if (t < 64)  outk[base * 32 + (t - 32)] = bv;
            else              outv[base * 64 + (t - 64)] = bv;
        } else {
            outf[(size_t)row * 384 + col] = val;
        }
    }
}

// ---------------------------------------------------------------------------
// v[bh][n][64] -> vt[bh][64][n]  (LDS tile transpose, coalesced both sides)
// ---------------------------------------------------------------------------
__global__ void vtrans_kernel(const unsigned short* __restrict__ v,
                              unsigned short* __restrict__ vt)
{
    __shared__ __align__(16) unsigned short tile[64][80];
    int bh = blockIdx.x, nb = blockIdx.y, t = threadIdx.x;
    #pragma unroll
    for (int rep = 0; rep < 2; ++rep) {
        int nl = (t >> 3) + rep * 32;
        int c0 = (t & 7) * 8;
        *(u32x4*)(&tile[nl][c0]) =
            *(const u32x4*)(v + ((size_t)bh * 1024 + nb * 64 + nl) * 64 + c0);
    }
    __syncthreads();
    #pragma unroll
    for (int rep = 0; rep < 2; ++rep) {
        int vd = (t >> 3) + rep * 32;
        int n0 = (t & 7) * 8;
        u16x8 o;
        #pragma unroll
        for (int i = 0; i < 8; ++i) o[i] = tile[n0 + i][vd];
        *(u16x8*)(vt + ((size_t)bh * 64 + vd) * 1024 + nb * 64 + n0) = o;
    }
}

// ---------------------------------------------------------------------------
// fused flash attention: wg = (qblk64, h, b), 4 waves x 16 q-rows.
// V^T tile double-buffered in LDS (loads for kb+1 issued at top of kb, written
// after PV, ONE barrier/iter).  K B-frags per-lane from global (L1-shared).
// bias as MFMA C-in; row-sum via ones-column MFMA; defer-max (THR=8).
// epilogue: /lsum, hardswish, hi/lo split -> Oaug[tok][1536]
// ---------------------------------------------------------------------------
__launch_bounds__(256, 4)
__global__ void attn_kernel(const unsigned short* __restrict__ q,
                            const unsigned short* __restrict__ kmat,
                            const unsigned short* __restrict__ vt,
                            const float* __restrict__ ab,
                            unsigned short* __restrict__ Oaug)
{
    __shared__ __align__(16) unsigned short Vls[2][64 * 64]; // swizzled [vd][key]
    __shared__ __align__(16) unsigned short Pls[4 * 16 * 64]; // per-wave P
    __shared__ float biasrow[1024];

    const int tid = threadIdx.x;
    const int lane = tid & 63, w = tid >> 6;
    const int l15 = lane & 15, lg = lane >> 4;
    const int qb = blockIdx.x, h = blockIdx.y, b = blockIdx.z;
    const int bh = b * 8 + h;

    for (int i = tid; i < 1024; i += 256) biasrow[i] = ab[h * 1024 + i];

    // Q A-frag (A: row=lane&15, k=(lane>>4)*8+i) — resident whole kernel
    const int qrowA = qb * 64 + w * 16 + l15;
    const bf16x8 aq = *(const bf16x8*)(q + ((size_t)bh * 1024 + qrowA) * 32 + lg * 8);

    // D-layout q-rows for this lane: qi = qb*64 + w*16 + lg*4 + j
    int xi[4], dy2[2][4];
    #pragma unroll
    for (int j = 0; j < 4; ++j) {
        int qi = qb * 64 + w * 16 + lg * 4 + j;
        xi[j] = qi >> 5;
        int yi = qi & 31;
        #pragma unroll
        for (int p = 0; p < 2; ++p) {
            int d = yi - (p * 16 + l15);
            dy2[p][j] = d < 0 ? -d : d;
        }
    }

    float m[4];
    f32x4 acc[4], accS;
    #pragma unroll
    for (int j = 0; j < 4; ++j) m[j] = -1e30f;
    #pragma unroll
    for (int cf = 0; cf < 4; ++cf) acc[cf] = (f32x4){0.f, 0.f, 0.f, 0.f};
    accS = (f32x4){0.f, 0.f, 0.f, 0.f};

    const short oneb = (short)0x3F80;
    const bf16x8 onesb = {oneb, oneb, oneb, oneb, oneb, oneb, oneb, oneb};

    const unsigned short* kbase = kmat + (size_t)bh * 1024 * 32 + lg * 8;

    // V staging geometry: thread t owns vd row svd = t>>2, 16-key chunk skq
    const int svd = tid >> 2, skq = tid & 3;
    const unsigned short* vsrc = vt + ((size_t)bh * 64 + svd) * 1024 + skq * 16;
    const int sbase = svd * 128;
    const int sxor = (svd & 7) << 4;

    // prolog: stage tile kb=0 into Vls[0]; barrier covers biasrow too
    u32x4 d0 = *(const u32x4*)(vsrc);
    u32x4 d1 = *(const u32x4*)(vsrc + 8);
    *(u32x4*)((char*)Vls[0] + sbase + ((skq * 32) ^ sxor)) = d0;
    *(u32x4*)((char*)Vls[0] + sbase + ((skq * 32 + 16) ^ sxor)) = d1;
    __syncthreads();

    for (int kb = 0; kb < 16; ++kb) {
        const int cur = kb & 1;
        // issue next V tile's global loads (latency hides under QK+softmax+PV)
        if (kb < 15) {
            d0 = *(const u32x4*)(vsrc + (kb + 1) * 64);
            d1 = *(const u32x4*)(vsrc + (kb + 1) * 64 + 8);
        }

        // QK^T with bias as C-in (B-frag from global k, L1-shared across waves)
        f32x4 s[4];
        __builtin_amdgcn_s_setprio(1);
        #pragma unroll
        for (int cf = 0; cf < 4; ++cf) {
            int xj = kb * 2 + (cf >> 1);
            f32x4 c;
            #pragma unroll
            for (int j = 0; j < 4; ++j) {
                int dx = xi[j] - xj; dx = dx < 0 ? -dx : dx;
                c[j] = biasrow[dx * 32 + dy2[cf & 1][j]];
            }
            const bf16x8 bk = *(const bf16x8*)(kbase + (size_t)(kb * 64 + cf * 16 + l15) * 32);
            s[cf] = __builtin_amdgcn_mfma_f32_16x16x32_bf16(aq, bk, c, 0, 0, 0);
        }
        __builtin_amdgcn_s_setprio(0);

        // row max (in-lane over cf, then 4-round shfl over l15)
        float nm[4];
        #pragma unroll
        for (int j = 0; j < 4; ++j) {
            float rm = fmaxf(fmaxf(s[0][j], s[1][j]), fmaxf(s[2][j], s[3][j]));
            rm = fmaxf(rm, __shfl_xor(rm, 1));
            rm = fmaxf(rm, __shfl_xor(rm, 2));
            rm = fmaxf(rm, __shfl_xor(rm, 4));
            rm = fmaxf(rm, __shfl_xor(rm, 8));
            nm[j] = rm;
        }
        // defer-max: only rescale when some row grew past THR=8
        bool grow = (nm[0] > m[0] + 8.f) | (nm[1] > m[1] + 8.f) |
                    (nm[2] > m[2] + 8.f) | (nm[3] > m[3] + 8.f);
        if (__any(grow)) {
            #pragma unroll
            for (int j = 0; j < 4; ++j) {
                float M = fmaxf(m[j], nm[j]);
                float al = __expf(m[j] - M);
                m[j] = M;
                #pragma unroll
                for (int cf = 0; cf < 4; ++cf) acc[cf][j] *= al;
                accS[j] *= al;
            }
        }

        // P = exp(s - m) -> per-wave LDS (bf16, XOR-swizzled rows)
        #pragma unroll
        for (int j = 0; j < 4; ++j) {
            int qrl = lg * 4 + j;
            int rxor = (qrl & 7) << 4;
            #pragma unroll
            for (int cf = 0; cf < 4; ++cf) {
                float pv = __expf(s[cf][j] - m[j]);
                *(unsigned short*)((char*)Pls + w * 2048 + qrl * 128 +
                                   ((cf * 32 + l15 * 2) ^ rxor)) = f2b(pv);
            }
        }
        __asm__ volatile("s_waitcnt lgkmcnt(0)" ::: "memory");

        // PV: A-frag = P rows, B-frag = V^T rows from swizzled LDS;
        // ones-column MFMA accumulates the row sums into accS (rides rescale).
        __builtin_amdgcn_s_setprio(1);
        #pragma unroll
        for (int ks = 0; ks < 2; ++ks) {
            const bf16x8 pa = *(const bf16x8*)((char*)Pls + w * 2048 + l15 * 128 +
                                               ((ks * 64 + lg * 16) ^ ((l15 & 7) << 4)));
            accS = __builtin_amdgcn_mfma_f32_16x16x32_bf16(pa, onesb, accS, 0, 0, 0);
            #pragma unroll
            for (int cf = 0; cf < 4; ++cf) {
                const bf16x8 vb = *(const bf16x8*)((char*)Vls[cur] + (cf * 16 + l15) * 128 +
                                                   ((ks * 64 + lg * 16) ^ (((cf * 16 + l15) & 7) << 4)));
                acc[cf] = __builtin_amdgcn_mfma_f32_16x16x32_bf16(pa, vb, acc[cf], 0, 0, 0);
            }
        }
        __builtin_amdgcn_s_setprio(0);

        // commit next V tile, then the single per-iteration barrier
        if (kb < 15) {
            *(u32x4*)((char*)Vls[cur ^ 1] + sbase + ((skq * 32) ^ sxor)) = d0;
            *(u32x4*)((char*)Vls[cur ^ 1] + sbase + ((skq * 32 + 16) ^ sxor)) = d1;
            __syncthreads();
        }
    }

    // epilogue: normalize, hardswish, hi/lo split into augmented activations
    float rinv[4];
    #pragma unroll
    for (int j = 0; j < 4; ++j) rinv[j] = 1.f / accS[j];
    #pragma unroll
    for (int cf = 0; cf < 4; ++cf)
    #pragma unroll
    for (int j = 0; j < 4; ++j) {
        float ov = acc[cf][j] * rinv[j];
        float hs = ov * fminf(fmaxf(ov + 3.f, 0.f), 6.f) * (1.f / 6.f);
        unsigned short hi = f2b(hs);
        unsigned short lo = f2b(hs - b2f(hi));
        size_t tok = (size_t)b * 1024 + qb * 64 + w * 16 + lg * 4 + j;
        int c = h * 64 + cf * 16 + l15;
        Oaug[tok * 1536 + c]        = hi;
        Oaug[tok * 1536 + 512 + c]  = hi;
        Oaug[tok * 1536 + 1024 + c] = lo;
    }
}

// ---------------------------------------------------------------------------
extern "C" void kernel_launch(void* const* d_in, const int* in_sizes, int n_in,
                              void* d_out, int out_size, void* d_ws, size_t ws_size,
                              hipStream_t stream)
{
    const float* x   = (const float*)d_in[0];
    const float* qw  = (const float*)d_in[1];
    const float* qg  = (const float*)d_in[2];
    const float* qbe = (const float*)d_in[3];
    const float* qmu = (const float*)d_in[4];
    const float* qva = (const float*)d_in[5];
    const float* pw  = (const float*)d_in[6];
    const float* pg  = (const float*)d_in[7];
    const float* pbe = (const float*)d_in[8];
    const float* pmu = (const float*)d_in[9];
    const float* pva = (const float*)d_in[10];
    const float* ab  = (const float*)d_in[11];
    // d_in[12] (bias_idxs) replicated arithmetically in-kernel

    char* ws = (char*)d_ws;
    size_t off = 0;
    auto alloc = [&](size_t bytes) {
        size_t o = off; off = (off + bytes + 255) & ~(size_t)255; return o;
    };

    size_t o_oaug = alloc((size_t)16384 * 1536 * 2); // Oaug (hi|hi|lo)
    size_t o_wT  = alloc((size_t)1024 * 384 * 2);
    size_t o_pwT = alloc((size_t)384 * 1536 * 2);
    size_t o_t1  = alloc(1024 * 4);
    size_t o_t2  = alloc(384 * 4);
    size_t o_q   = alloc((size_t)16 * 8 * 1024 * 32 * 2);
    size_t o_k   = alloc((size_t)16 * 8 * 1024 * 32 * 2);
    size_t o_v   = alloc((size_t)16 * 8 * 1024 * 64 * 2);
    size_t o_vt  = alloc((size_t)16 * 8 * 1024 * 64 * 2);

    unsigned short* Oaug = (unsigned short*)(ws + o_oaug);
    unsigned short* wT   = (unsigned short*)(ws + o_wT);
    unsigned short* pwT  = (unsigned short*)(ws + o_pwT);
    float* t1 = (float*)(ws + o_t1);
    float* t2 = (float*)(ws + o_t2);
    unsigned short* qb_ = (unsigned short*)(ws + o_q);
    unsigned short* kb_ = (unsigned short*)(ws + o_k);
    unsigned short* vb_ = (unsigned short*)(ws + o_v);
    unsigned short* vtb = (unsigned short*)(ws + o_vt);

    prep_w_qkv<<<1536, 256, 0, stream>>>(qw, qg, qbe, qmu, qva, wT, t1);
    prep_w_proj<<<768, 256, 0, stream>>>(pw, pg, pbe, pmu, pva, pwT, t2);

    // qkv GEMM with fused fp32->bf16 A-staging (prep_x eliminated)
    gemm_bt<128, 128, 0, 1><<<dim3(128, 8), 256, 0, stream>>>(
        x, wT, 384, t1, qb_, kb_, vb_, nullptr);

    vtrans_kernel<<<dim3(128, 16), 256, 0, stream>>>(vb_, vtb);

    attn_kernel<<<dim3(16, 8, 16), 256, 0, stream>>>(qb_, kb_, vtb, ab, Oaug);

    gemm_bt<64, 128, 1, 0><<<dim3(256, 3), 256, 0, stream>>>(
        Oaug, pwT, 1536, t2, nullptr, nullptr, nullptr, (float*)d_out);
}